// Round 3
// baseline (541.008 us; speedup 1.0000x reference)
//
#include <hip/hip_runtime.h>

// BLOOM attention block on MI355X (gfx950).
// QKV GEMM: 256x256 8-phase pipelined kernel (T2+T3+T4+T5), counted vmcnt.
// Final GEMM + attention: proven 128-tile structure from round 2.
// Workspace layout (requires ws_size >= 160 MiB): see kernel_launch.

#define SEQL 2048
#define HIDN 4096
#define NHEAD 32
#define HDIM 128
#define H3 12288

typedef __bf16 bf16x8 __attribute__((ext_vector_type(8)));
typedef float f32x4 __attribute__((ext_vector_type(4)));
typedef unsigned short u16x8 __attribute__((ext_vector_type(8)));

__device__ __forceinline__ unsigned short f2bf(float f) {
  union { float f; unsigned u; } v; v.f = f;
  return (unsigned short)((v.u + 0x7FFFu + ((v.u >> 16) & 1u)) >> 16);
}

__device__ __forceinline__ void gload_lds16(const void* g, void* l) {
  __builtin_amdgcn_global_load_lds(
      (const __attribute__((address_space(1))) void*)g,
      (__attribute__((address_space(3))) void*)l, 16, 0, 0);
}

__global__ __launch_bounds__(256) void cvt_f32_bf16(
    const float* __restrict__ in, unsigned short* __restrict__ out, long long n) {
  long long i = ((long long)blockIdx.x * blockDim.x + threadIdx.x) * 8;
  long long stride = (long long)gridDim.x * blockDim.x * 8;
  for (; i < n; i += stride) {
    float4 a = *(const float4*)(in + i);
    float4 b = *(const float4*)(in + i + 4);
    u16x8 o;
    o[0] = f2bf(a.x); o[1] = f2bf(a.y); o[2] = f2bf(a.z); o[3] = f2bf(a.w);
    o[4] = f2bf(b.x); o[5] = f2bf(b.y); o[6] = f2bf(b.z); o[7] = f2bf(b.w);
    *(u16x8*)(out + i) = o;
  }
}

// ---------------------------------------------------------------------------
// 256x256 8-phase QKV GEMM. C[M=2048, N=12288] = A * B^T, K=4096, BK=64.
// 8 waves (512 thr). Phase (mh,nh): whole-block C-quadrant 128x128; wave w
// computes its 64x32 piece (4x2 frags) over K=64 -> 16 MFMA/phase.
// LDS: 2 buf x {A,B} x 2 halves x [128 rows][64 cols] bf16 = 128 KiB.
// Swizzle (as r1/r2, conflict-free verified): LDS[r][j16] = G[r][j16^(r&7)],
// reads XOR byte ^ ((r&7)<<4). Staging = linear-dest global_load_lds w/
// pre-swizzled source chunk (row&7 == lane>>3 for 8-row/1KB chunks).
// Pipeline: while computing tile t from buf[t&1], phases 0..3 stage tile
// t+1's halves [Ah0,Bh0,Bh1,Ah1] into buf[~t&1]. vmcnt(4) at ph0/1/3
// protects the NEXT phase's ds_reads (vmcnt retires in order); last tile
// drains 2->0. Never vmcnt(0) in steady state (T4).
// ---------------------------------------------------------------------------
__global__ __launch_bounds__(512, 2) void gemm256_qkv(
    const unsigned short* __restrict__ A, const unsigned short* __restrict__ B,
    const float* __restrict__ bias,
    unsigned short* __restrict__ q_bf, unsigned short* __restrict__ k_bf,
    unsigned short* __restrict__ v_t) {
  __shared__ unsigned short lds[2][2][2][8192];  // [buf][A/B][half][128*64]

  const int tid = threadIdx.x;
  const int l = tid & 63;
  const int w = tid >> 6;
  const int K = HIDN;

  // XCD-bijective tile map: 384 blocks = 8(M) x 48(N); XCD c gets lin
  // [48c,48c+48) = N-panels [6c,6c+6) over all M -> per-XCD L2 working set
  // = 6 B-panels (12 MB) + A (16 MB).
  const int b = blockIdx.x;
  const int lin = (b & 7) * 48 + (b >> 3);
  const int tm0 = (lin & 7) * 256;
  const int tn0 = (lin >> 3) * 256;

  const int lr = l >> 3;          // staging row-in-chunk
  const int lc = (l & 7) ^ lr;    // pre-swizzled source 16B chunk
  const int wm = (w >> 2) * 64;   // wave row offset within A-half
  const int wn = (w & 3) * 32;    // wave row offset within B-half

  f32x4 acc[2][2][4][2] = {};     // [mh][nh][mi][ni]

  auto stageA = [&](int bf, int mh, int kt) {
#pragma unroll
    for (int i = 0; i < 2; ++i) {
      const int c = w * 2 + i;    // 1KB chunk = 8 rows
      gload_lds16(&A[(long long)(tm0 + mh * 128 + c * 8 + lr) * K + kt + lc * 8],
                  (char*)&lds[bf][0][mh][0] + c * 1024);
    }
  };
  auto stageB = [&](int bf, int nh, int kt) {
#pragma unroll
    for (int i = 0; i < 2; ++i) {
      const int c = w * 2 + i;
      gload_lds16(&B[(long long)(tn0 + nh * 128 + c * 8 + lr) * K + kt + lc * 8],
                  (char*)&lds[bf][1][nh][0] + c * 1024);
    }
  };

  // Prologue: tile 0 halves in need-order; confirm first two halves.
  stageA(0, 0, 0);
  stageB(0, 0, 0);
  stageB(0, 1, 0);
  stageA(0, 1, 0);
  asm volatile("s_waitcnt vmcnt(4)" ::: "memory");
  __builtin_amdgcn_s_barrier();

  const int NT = K / 64;
  for (int t = 0; t < NT; ++t) {
    const int bf = t & 1, nb = bf ^ 1;
    const int kt1 = (t + 1) * 64;
    const bool pf = (t + 1 < NT);
#pragma unroll
    for (int ph = 0; ph < 4; ++ph) {
      const int mh = ph >> 1, nh = ph & 1;
      // ds-load this phase's fragments (protected by waits through ph-1)
      bf16x8 af[4][2], bfr[2][2];
#pragma unroll
      for (int mi = 0; mi < 4; ++mi) {
        const int r = wm + mi * 16 + (l & 15);
#pragma unroll
        for (int kk = 0; kk < 2; ++kk)
          af[mi][kk] = *(const bf16x8*)((const char*)&lds[bf][0][mh][0] +
              r * 128 + ((kk * 64 + (l >> 4) * 16) ^ ((l & 7) << 4)));
      }
#pragma unroll
      for (int ni = 0; ni < 2; ++ni) {
        const int r = wn + ni * 16 + (l & 15);
#pragma unroll
        for (int kk = 0; kk < 2; ++kk)
          bfr[ni][kk] = *(const bf16x8*)((const char*)&lds[bf][1][nh][0] +
              r * 128 + ((kk * 64 + (l >> 4) * 16) ^ ((l & 7) << 4)));
      }
      // stage one half of tile t+1 + counted wait protecting phase ph+1
      if (ph == 0) {
        if (pf) { stageA(nb, 0, kt1); asm volatile("s_waitcnt vmcnt(4)" ::: "memory"); }
        else    { asm volatile("s_waitcnt vmcnt(2)" ::: "memory"); }
      } else if (ph == 1) {
        if (pf) { stageB(nb, 0, kt1); asm volatile("s_waitcnt vmcnt(4)" ::: "memory"); }
        else    { asm volatile("s_waitcnt vmcnt(0)" ::: "memory"); }
      } else if (ph == 2) {
        if (pf) { stageB(nb, 1, kt1); }  // ph3's halves already confirmed @ph1
      } else {
        if (pf) { stageA(nb, 1, kt1); asm volatile("s_waitcnt vmcnt(4)" ::: "memory"); }
      }
      __builtin_amdgcn_s_barrier();
      asm volatile("s_waitcnt lgkmcnt(0)" ::: "memory");
      __builtin_amdgcn_s_setprio(1);
#pragma unroll
      for (int kk = 0; kk < 2; ++kk)
#pragma unroll
        for (int mi = 0; mi < 4; ++mi)
#pragma unroll
          for (int ni = 0; ni < 2; ++ni)
            acc[mh][nh][mi][ni] = __builtin_amdgcn_mfma_f32_16x16x32_bf16(
                af[mi][kk], bfr[ni][kk], acc[mh][nh][mi][ni], 0, 0, 0);
      __builtin_amdgcn_s_setprio(0);
      __builtin_amdgcn_s_barrier();
    }
  }

  // Epilogue: bias + interleaved QKV scatter (D: col=lane&15, row=(l>>4)*4+r)
#pragma unroll
  for (int mh = 0; mh < 2; ++mh)
#pragma unroll
    for (int nh = 0; nh < 2; ++nh)
#pragma unroll
      for (int mi = 0; mi < 4; ++mi)
#pragma unroll
        for (int ni = 0; ni < 2; ++ni) {
          const int col = tn0 + nh * 128 + wn + ni * 16 + (l & 15);
          const float bv = bias[col];
          const int head = col / 384;
          const int rem = col - head * 384;
          const int which = rem >> 7;
          const int d = rem & 127;
#pragma unroll
          for (int r = 0; r < 4; ++r) {
            const int row = tm0 + mh * 128 + wm + mi * 16 + (l >> 4) * 4 + r;
            const unsigned short bv16 = f2bf(acc[mh][nh][mi][ni][r] + bv);
            if (which == 0)
              q_bf[(long long)(head * SEQL + row) * HDIM + d] = bv16;
            else if (which == 1)
              k_bf[(long long)(head * SEQL + row) * HDIM + d] = bv16;
            else
              v_t[(long long)(head * HDIM + d) * SEQL + row] = bv16;
          }
        }
}

// ---------------------------------------------------------------------------
// 128x128 GEMM (round-2 proven) — used for the output projection.
// C = A * B^T + bias[col] + residual, fp32 out.
// ---------------------------------------------------------------------------
__global__ __launch_bounds__(256) void gemm_nt_res(
    const unsigned short* __restrict__ A, const unsigned short* __restrict__ B,
    int M, int N, int K,
    const float* __restrict__ bias, const float* __restrict__ residual,
    float* __restrict__ outf) {
  __shared__ unsigned short As[128 * 64];
  __shared__ unsigned short Bs[128 * 64];

  const int tid = threadIdx.x;
  const int l = tid & 63;
  const int w = tid >> 6;
  const int wr = (w >> 1) * 64;
  const int wc = (w & 1) * 64;
  const int tm0 = blockIdx.x * 128;
  const int tn0 = blockIdx.y * 128;

  const int lr = l >> 3;
  const int lc = (l & 7) ^ lr;

  f32x4 acc[4][4] = {};

  for (int kt = 0; kt < K; kt += 64) {
    __syncthreads();
#pragma unroll
    for (int i = 0; i < 4; ++i) {
      const int row = w * 32 + i * 8 + lr;
      gload_lds16(&A[(long long)(tm0 + row) * K + kt + lc * 8],
                  (char*)As + (w * 4 + i) * 1024);
      gload_lds16(&B[(long long)(tn0 + row) * K + kt + lc * 8],
                  (char*)Bs + (w * 4 + i) * 1024);
    }
    __syncthreads();
#pragma unroll
    for (int kk = 0; kk < 2; ++kk) {
      const int colb = kk * 64 + (l >> 4) * 16;
      bf16x8 af[4], bfr[4];
#pragma unroll
      for (int m = 0; m < 4; ++m) {
        int row = wr + m * 16 + (l & 15);
        af[m] = *(const bf16x8*)((char*)As + row * 128 + (colb ^ ((row & 7) << 4)));
      }
#pragma unroll
      for (int n = 0; n < 4; ++n) {
        int row = wc + n * 16 + (l & 15);
        bfr[n] = *(const bf16x8*)((char*)Bs + row * 128 + (colb ^ ((row & 7) << 4)));
      }
#pragma unroll
      for (int m = 0; m < 4; ++m)
#pragma unroll
        for (int n = 0; n < 4; ++n)
          acc[m][n] = __builtin_amdgcn_mfma_f32_16x16x32_bf16(af[m], bfr[n], acc[m][n], 0, 0, 0);
    }
  }

#pragma unroll
  for (int m = 0; m < 4; ++m)
#pragma unroll
    for (int n = 0; n < 4; ++n) {
      const int col = tn0 + wc + n * 16 + (l & 15);
      const float bv = bias[col];
#pragma unroll
      for (int r = 0; r < 4; ++r) {
        const int rowg = tm0 + wr + m * 16 + (l >> 4) * 4 + r;
        const long long idx = (long long)rowg * N + col;
        outf[idx] = acc[m][n][r] + bv + residual[idx];
      }
    }
}

// ---------------------------------------------------------------------------
// Flash attention with alibi + causal mask (round-2 proven).
// ---------------------------------------------------------------------------
__global__ __launch_bounds__(256) void attn_fwd(
    const unsigned short* __restrict__ q_bf, const unsigned short* __restrict__ k_bf,
    const unsigned short* __restrict__ v_t, const float* __restrict__ alibi,
    unsigned short* __restrict__ ctx_bf) {
  __shared__ unsigned short Ks[64 * 128];
  __shared__ unsigned short Vs[128 * 64];
  __shared__ unsigned short Ps[4][16 * 64];
  __shared__ float Al[SEQL];

  const int tid = threadIdx.x;
  const int l = tid & 63;
  const int w = tid >> 6;
  const int h = blockIdx.x;
  const int qt = blockIdx.y * 64;
  const int qw = qt + w * 16;

  for (int i = tid; i < SEQL; i += 256) Al[i] = alibi[h * SEQL + i];

  bf16x8 qf[4];
  {
    const unsigned short* qp =
        &q_bf[(long long)(h * SEQL + qw + (l & 15)) * HDIM + (l >> 4) * 8];
#pragma unroll
    for (int kk = 0; kk < 4; ++kk) qf[kk] = *(const bf16x8*)(qp + kk * 32);
  }

  f32x4 oacc[8] = {};
  float mrun[4] = {-__builtin_inff(), -__builtin_inff(), -__builtin_inff(), -__builtin_inff()};
  float lrun[4] = {0.f, 0.f, 0.f, 0.f};
  const float inv_norm = 0.08838834764831845f;

  const int kR = l >> 4, kC = l & 15;
  const int vR = l >> 3, vC = (l & 7) ^ vR;

  const int ntiles = blockIdx.y + 1;
  for (int t = 0; t < ntiles; ++t) {
    const int kv0 = t * 64;
    __syncthreads();
#pragma unroll
    for (int i = 0; i < 4; ++i) {
      const int krow = w * 16 + i * 4 + kR;
      const int ksrc = kC ^ ((i & 1) * 4 + kR);
      gload_lds16(&k_bf[(long long)(h * SEQL + kv0 + krow) * HDIM + ksrc * 8],
                  (char*)Ks + (w * 4 + i) * 1024);
      const int vrow = w * 32 + i * 8 + vR;
      gload_lds16(&v_t[(long long)(h * HDIM + vrow) * SEQL + kv0 + vC * 8],
                  (char*)Vs + (w * 4 + i) * 1024);
    }
    __syncthreads();

    f32x4 sacc[4] = {};
#pragma unroll
    for (int kk = 0; kk < 4; ++kk) {
      const int colb = kk * 64 + (l >> 4) * 16;
#pragma unroll
      for (int n = 0; n < 4; ++n) {
        int row = n * 16 + (l & 15);
        bf16x8 kf = *(const bf16x8*)((char*)Ks + row * 256 + (colb ^ ((row & 7) << 4)));
        sacc[n] = __builtin_amdgcn_mfma_f32_16x16x32_bf16(qf[kk], kf, sacc[n], 0, 0, 0);
      }
    }

    float sc[4][4];
#pragma unroll
    for (int n = 0; n < 4; ++n) {
      const int kv = kv0 + n * 16 + (l & 15);
      const float al = Al[kv];
#pragma unroll
      for (int r = 0; r < 4; ++r) {
        const int qrow = qw + (l >> 4) * 4 + r;
        float v = al + inv_norm * sacc[n][r];
        sc[n][r] = (kv > qrow) ? -__builtin_inff() : v;
      }
    }

#pragma unroll
    for (int r = 0; r < 4; ++r) {
      float m0 = fmaxf(fmaxf(sc[0][r], sc[1][r]), fmaxf(sc[2][r], sc[3][r]));
      m0 = fmaxf(m0, __shfl_xor(m0, 1, 64));
      m0 = fmaxf(m0, __shfl_xor(m0, 2, 64));
      m0 = fmaxf(m0, __shfl_xor(m0, 4, 64));
      m0 = fmaxf(m0, __shfl_xor(m0, 8, 64));
      const float mnew = fmaxf(mrun[r], m0);
      float p0 = 0.f;
#pragma unroll
      for (int n = 0; n < 4; ++n) {
        const float pv = __expf(sc[n][r] - mnew);
        sc[n][r] = pv;
        p0 += pv;
      }
      p0 += __shfl_xor(p0, 1, 64);
      p0 += __shfl_xor(p0, 2, 64);
      p0 += __shfl_xor(p0, 4, 64);
      p0 += __shfl_xor(p0, 8, 64);
      const float scale = __expf(mrun[r] - mnew);
      mrun[r] = mnew;
      lrun[r] = lrun[r] * scale + p0;
#pragma unroll
      for (int n2 = 0; n2 < 8; ++n2) oacc[n2][r] *= scale;
    }

#pragma unroll
    for (int n = 0; n < 4; ++n)
#pragma unroll
      for (int r = 0; r < 4; ++r) {
        const int row = (l >> 4) * 4 + r;
        const int colp = n * 16 + (l & 15);
        *(unsigned short*)((char*)Ps[w] + row * 128 + ((colp * 2) ^ ((row & 7) << 4))) =
            f2bf(sc[n][r]);
      }
    __threadfence_block();
    bf16x8 pf[2];
#pragma unroll
    for (int kk2 = 0; kk2 < 2; ++kk2) {
      const int row = l & 15;
      const int colb = kk2 * 64 + (l >> 4) * 16;
      pf[kk2] = *(const bf16x8*)((char*)Ps[w] + row * 128 + (colb ^ ((row & 7) << 4)));
    }

#pragma unroll
    for (int n2 = 0; n2 < 8; ++n2) {
#pragma unroll
      for (int kk2 = 0; kk2 < 2; ++kk2) {
        const int row = n2 * 16 + (l & 15);
        const int colb = kk2 * 64 + (l >> 4) * 16;
        bf16x8 vf = *(const bf16x8*)((char*)Vs + row * 128 + (colb ^ ((row & 7) << 4)));
        oacc[n2] = __builtin_amdgcn_mfma_f32_16x16x32_bf16(pf[kk2], vf, oacc[n2], 0, 0, 0);
      }
    }
  }

#pragma unroll
  for (int n2 = 0; n2 < 8; ++n2)
#pragma unroll
    for (int r = 0; r < 4; ++r) {
      const int qrow = qw + (l >> 4) * 4 + r;
      const int col = h * HDIM + n2 * 16 + (l & 15);
      ctx_bf[(long long)qrow * HIDN + col] = f2bf(oacc[n2][r] / lrun[r]);
    }
}

extern "C" void kernel_launch(void* const* d_in, const int* in_sizes, int n_in,
                              void* d_out, int out_size, void* d_ws, size_t ws_size,
                              hipStream_t stream) {
  const float* hidden = (const float*)d_in[0];
  const float* residual = (const float*)d_in[1];
  const float* alibi = (const float*)d_in[2];
  // d_in[3]: attention_mask (bool) — causal mask computed analytically
  const float* Wqkv = (const float*)d_in[4];
  const float* bqkv = (const float*)d_in[5];
  const float* Wd = (const float*)d_in[6];
  const float* bd = (const float*)d_in[7];
  float* out = (float*)d_out;

  char* ws = (char*)d_ws;
  const size_t MB16 = 16777216;
  unsigned short* q_bf = (unsigned short*)(ws);
  unsigned short* k_bf = (unsigned short*)(ws + MB16);
  unsigned short* v_t = (unsigned short*)(ws + 2 * MB16);
  unsigned short* hid_bf = (unsigned short*)(ws + 3 * MB16);
  unsigned short* wqkv_bf = (unsigned short*)(ws + 4 * MB16);  // 96 MiB
  unsigned short* wd_bf = (unsigned short*)(ws + 4 * MB16);    // reuse after QKV GEMM
  unsigned short* ctx_bf = (unsigned short*)(ws + 4 * MB16 + 33554432);

  // 1. convert inputs to bf16
  cvt_f32_bf16<<<4096, 256, 0, stream>>>(hidden, hid_bf, (long long)SEQL * HIDN);
  cvt_f32_bf16<<<24576, 256, 0, stream>>>(Wqkv, wqkv_bf, (long long)H3 * HIDN);

  // 2. QKV projection (256^2 8-phase) with interleaved-scatter epilogue
  gemm256_qkv<<<384, 512, 0, stream>>>(hid_bf, wqkv_bf, bqkv, q_bf, k_bf, v_t);

  // 3. convert Wd (reuses Wqkv region — stream-ordered after QKV GEMM)
  cvt_f32_bf16<<<8192, 256, 0, stream>>>(Wd, wd_bf, (long long)HIDN * HIDN);

  // 4. flash attention (alibi + causal)
  attn_fwd<<<dim3(NHEAD, SEQL / 64), 256, 0, stream>>>(q_bf, k_bf, v_t, alibi, ctx_bf);

  // 5. output projection + bias + residual (fp32 out)
  gemm_nt_res<<<dim3(SEQL / 128, HIDN / 128), 256, 0, stream>>>(
      ctx_bf, wd_bf, SEQL, HIDN, HIDN, bd, residual, out);
}

// Round 4
// 513.997 us; speedup vs baseline: 1.0526x; 1.0526x over previous
//
#include <hip/hip_runtime.h>

// BLOOM attention block on MI355X (gfx950).
// QKV GEMM: 256x256 8-phase pipelined kernel, m201-style: operand-register
// reuse (24 ds_read_b128/tile/wave) + next-phase ds_reads inside the MFMA
// window + counted vmcnt (never 0 in steady state) + setprio + XCD swizzle.
// Final GEMM + attention: proven 128-tile structure from round 2.

#define SEQL 2048
#define HIDN 4096
#define NHEAD 32
#define HDIM 128
#define H3 12288

typedef __bf16 bf16x8 __attribute__((ext_vector_type(8)));
typedef float f32x4 __attribute__((ext_vector_type(4)));
typedef unsigned short u16x8 __attribute__((ext_vector_type(8)));

__device__ __forceinline__ unsigned short f2bf(float f) {
  union { float f; unsigned u; } v; v.f = f;
  return (unsigned short)((v.u + 0x7FFFu + ((v.u >> 16) & 1u)) >> 16);
}

__device__ __forceinline__ void gload_lds16(const void* g, void* l) {
  __builtin_amdgcn_global_load_lds(
      (const __attribute__((address_space(1))) void*)g,
      (__attribute__((address_space(3))) void*)l, 16, 0, 0);
}

#define BAR() __builtin_amdgcn_s_barrier()
#define SCHED0() __builtin_amdgcn_sched_barrier(0x7)  // only ALU may cross
#define VM(n) asm volatile("s_waitcnt vmcnt(" #n ")" ::: "memory")

__global__ __launch_bounds__(256) void cvt_f32_bf16(
    const float* __restrict__ in, unsigned short* __restrict__ out, long long n) {
  long long i = ((long long)blockIdx.x * blockDim.x + threadIdx.x) * 8;
  long long stride = (long long)gridDim.x * blockDim.x * 8;
  for (; i < n; i += stride) {
    float4 a = *(const float4*)(in + i);
    float4 b = *(const float4*)(in + i + 4);
    u16x8 o;
    o[0] = f2bf(a.x); o[1] = f2bf(a.y); o[2] = f2bf(a.z); o[3] = f2bf(a.w);
    o[4] = f2bf(b.x); o[5] = f2bf(b.y); o[6] = f2bf(b.z); o[7] = f2bf(b.w);
    *(u16x8*)(out + i) = o;
  }
}

// ---------------------------------------------------------------------------
// 256x256 8-phase QKV GEMM. C[2048,12288] = A * B^T, K=4096, BK=64.
// 8 waves 2Mx4N; per-wave C = 128x64; quadrant (mh,nh) = 64x32 -> 16 MFMA.
// Reg sets: A0s/A1s (8 b128 each), B0s/B1s (4 each) persist across phases;
// only 24 ds_read_b128 per tile per wave. Phase window:
//   [stage 1 half of tile t+1; vmcnt(4)] BAR [16 MFMA ; ds_reads for next
//   phase] BAR    (sched_barrier(0x7) pins memory ops inside windows)
// Ledger (first-use >= 2 phases after issue, all forced by the vmcnt(4)
// chain): A0'(stg ph0, rd ph3-window), B0'(ph1, ph3-w), B1'(ph2, +1.ph0-w),
// A1'(ph3, +1.ph1-w). Tail t=NT-1: vmcnt(2)@ph0, vmcnt(0)@ph1.
// ---------------------------------------------------------------------------
__global__ __launch_bounds__(512, 2) void gemm256_qkv(
    const unsigned short* __restrict__ A, const unsigned short* __restrict__ B,
    const float* __restrict__ bias,
    unsigned short* __restrict__ q_bf, unsigned short* __restrict__ k_bf,
    unsigned short* __restrict__ v_t) {
  __shared__ unsigned short Ab[2][2][8192];  // [buf][half][128 rows * 64 cols]
  __shared__ unsigned short Bb[2][2][8192];

  const int tid = threadIdx.x;
  const int l = tid & 63;
  const int w = tid >> 6;
  const int K = HIDN;

  // XCD-bijective tile map: 384 = 8 XCD * 48; XCD c -> N-panels [6c,6c+6).
  const int b = blockIdx.x;
  const int lin = (b & 7) * 48 + (b >> 3);
  const int tm0 = (lin & 7) * 256;
  const int tn0 = (lin >> 3) * 256;

  const int lr = l >> 3;          // staging row-in-8-row-chunk
  const int lc = (l & 7) ^ lr;    // pre-swizzled source 16B chunk
  const int wm = w >> 2;          // A-half this wave consumes (0/1)
  const int wn = w & 3;           // col group; B-half = wn>>1
  const int bhalf = wn >> 1;
  const int brow0 = (wn & 1) * 64;

  f32x4 acc[2][2][4][2] = {};     // [mh][nh][mi][ni]
  bf16x8 A0s[4][2], A1s[4][2], B0s[2][2], B1s[2][2];

  auto stA = [&](int tt, int h) {
#pragma unroll
    for (int i = 0; i < 2; ++i) {
      const int c = w * 2 + i;
      gload_lds16(&A[(long long)(tm0 + h * 128 + c * 8 + lr) * K + tt * 64 + lc * 8],
                  (char*)&Ab[tt & 1][h][0] + c * 1024);
    }
  };
  auto stB = [&](int tt, int h) {
#pragma unroll
    for (int i = 0; i < 2; ++i) {
      const int c = w * 2 + i;
      gload_lds16(&B[(long long)(tn0 + h * 128 + c * 8 + lr) * K + tt * 64 + lc * 8],
                  (char*)&Bb[tt & 1][h][0] + c * 1024);
    }
  };
  auto rdA = [&](bf16x8 (&dst)[4][2], int bufi, int mh) {
#pragma unroll
    for (int mi = 0; mi < 4; ++mi) {
      const int r = mh * 64 + mi * 16 + (l & 15);
#pragma unroll
      for (int kk = 0; kk < 2; ++kk)
        dst[mi][kk] = *(const bf16x8*)((const char*)&Ab[bufi][wm][0] +
            r * 128 + ((kk * 64 + (l >> 4) * 16) ^ ((r & 7) << 4)));
    }
  };
  auto rdB = [&](bf16x8 (&dst)[2][2], int bufi, int nh) {
#pragma unroll
    for (int ni = 0; ni < 2; ++ni) {
      const int r = brow0 + nh * 32 + ni * 16 + (l & 15);
#pragma unroll
      for (int kk = 0; kk < 2; ++kk)
        dst[ni][kk] = *(const bf16x8*)((const char*)&Bb[bufi][bhalf][0] +
            r * 128 + ((kk * 64 + (l >> 4) * 16) ^ ((r & 7) << 4)));
    }
  };

#define MFMA16(As_, Bs_, mh_, nh_)                                            \
  __builtin_amdgcn_s_setprio(1);                                              \
  _Pragma("unroll") for (int kk = 0; kk < 2; ++kk)                            \
    _Pragma("unroll") for (int mi = 0; mi < 4; ++mi)                          \
      _Pragma("unroll") for (int ni = 0; ni < 2; ++ni)                        \
        acc[mh_][nh_][mi][ni] = __builtin_amdgcn_mfma_f32_16x16x32_bf16(      \
            As_[mi][kk], Bs_[ni][kk], acc[mh_][nh_][mi][ni], 0, 0, 0);        \
  __builtin_amdgcn_s_setprio(0);

  // Prologue: tile 0 (order A0,B0,B1,A1); force first three; pre-read A0,B0.
  stA(0, 0); stB(0, 0); stB(0, 1); stA(0, 1);
  VM(2);
  BAR();
  SCHED0();
  rdA(A0s, 0, 0);
  rdB(B0s, 0, 0);
  SCHED0();

  const int NT = K / 64;
  for (int t = 0; t < NT; ++t) {
    const int bf = t & 1;
    const bool pf = (t + 1) < NT;
    // ---- ph0: MFMA(A0,B0) | reads B1(t) ----
    if (pf) { stA(t + 1, 0); VM(4); } else { VM(2); }
    BAR(); SCHED0();
    MFMA16(A0s, B0s, 0, 0);
    rdB(B1s, bf, 1);
    SCHED0(); BAR();
    // ---- ph1: MFMA(A0,B1) | reads A1(t) ----
    if (pf) { stB(t + 1, 0); VM(4); } else { VM(0); }
    BAR(); SCHED0();
    MFMA16(A0s, B1s, 0, 1);
    rdA(A1s, bf, 1);
    SCHED0(); BAR();
    // ---- ph2: MFMA(A1,B0) | no reads ----
    if (pf) { stB(t + 1, 1); }
    BAR(); SCHED0();
    MFMA16(A1s, B0s, 1, 0);
    SCHED0(); BAR();
    // ---- ph3: MFMA(A1,B1) | reads A0(t+1), B0(t+1) ----
    if (pf) { stA(t + 1, 1); VM(4); }
    BAR(); SCHED0();
    MFMA16(A1s, B1s, 1, 1);
    if (pf) {
      rdA(A0s, bf ^ 1, 0);
      rdB(B0s, bf ^ 1, 0);
    }
    SCHED0(); BAR();
  }

  // Epilogue: bias + interleaved QKV scatter. D: col=lane&15, row=(l>>4)*4+r.
#pragma unroll
  for (int mh = 0; mh < 2; ++mh)
#pragma unroll
    for (int nh = 0; nh < 2; ++nh)
#pragma unroll
      for (int mi = 0; mi < 4; ++mi)
#pragma unroll
        for (int ni = 0; ni < 2; ++ni) {
          const int col = tn0 + wn * 64 + nh * 32 + ni * 16 + (l & 15);
          const float bv = bias[col];
          const int head = col / 384;
          const int rem = col - head * 384;
          const int which = rem >> 7;
          const int d = rem & 127;
#pragma unroll
          for (int r = 0; r < 4; ++r) {
            const int row = tm0 + wm * 128 + mh * 64 + mi * 16 + (l >> 4) * 4 + r;
            const unsigned short bv16 = f2bf(acc[mh][nh][mi][ni][r] + bv);
            if (which == 0)
              q_bf[(long long)(head * SEQL + row) * HDIM + d] = bv16;
            else if (which == 1)
              k_bf[(long long)(head * SEQL + row) * HDIM + d] = bv16;
            else
              v_t[(long long)(head * HDIM + d) * SEQL + row] = bv16;
          }
        }
}

// ---------------------------------------------------------------------------
// 128x128 GEMM (round-2 proven) — output projection + bias + residual.
// ---------------------------------------------------------------------------
__global__ __launch_bounds__(256) void gemm_nt_res(
    const unsigned short* __restrict__ A, const unsigned short* __restrict__ B,
    int M, int N, int K,
    const float* __restrict__ bias, const float* __restrict__ residual,
    float* __restrict__ outf) {
  __shared__ unsigned short As[128 * 64];
  __shared__ unsigned short Bs[128 * 64];

  const int tid = threadIdx.x;
  const int l = tid & 63;
  const int w = tid >> 6;
  const int wr = (w >> 1) * 64;
  const int wc = (w & 1) * 64;
  const int tm0 = blockIdx.x * 128;
  const int tn0 = blockIdx.y * 128;

  const int lr = l >> 3;
  const int lc = (l & 7) ^ lr;

  f32x4 acc[4][4] = {};

  for (int kt = 0; kt < K; kt += 64) {
    __syncthreads();
#pragma unroll
    for (int i = 0; i < 4; ++i) {
      const int row = w * 32 + i * 8 + lr;
      gload_lds16(&A[(long long)(tm0 + row) * K + kt + lc * 8],
                  (char*)As + (w * 4 + i) * 1024);
      gload_lds16(&B[(long long)(tn0 + row) * K + kt + lc * 8],
                  (char*)Bs + (w * 4 + i) * 1024);
    }
    __syncthreads();
#pragma unroll
    for (int kk = 0; kk < 2; ++kk) {
      const int colb = kk * 64 + (l >> 4) * 16;
      bf16x8 af[4], bfr[4];
#pragma unroll
      for (int m = 0; m < 4; ++m) {
        int row = wr + m * 16 + (l & 15);
        af[m] = *(const bf16x8*)((char*)As + row * 128 + (colb ^ ((row & 7) << 4)));
      }
#pragma unroll
      for (int n = 0; n < 4; ++n) {
        int row = wc + n * 16 + (l & 15);
        bfr[n] = *(const bf16x8*)((char*)Bs + row * 128 + (colb ^ ((row & 7) << 4)));
      }
#pragma unroll
      for (int m = 0; m < 4; ++m)
#pragma unroll
        for (int n = 0; n < 4; ++n)
          acc[m][n] = __builtin_amdgcn_mfma_f32_16x16x32_bf16(af[m], bfr[n], acc[m][n], 0, 0, 0);
    }
  }

#pragma unroll
  for (int m = 0; m < 4; ++m)
#pragma unroll
    for (int n = 0; n < 4; ++n) {
      const int col = tn0 + wc + n * 16 + (l & 15);
      const float bv = bias[col];
#pragma unroll
      for (int r = 0; r < 4; ++r) {
        const int rowg = tm0 + wr + m * 16 + (l >> 4) * 4 + r;
        const long long idx = (long long)rowg * N + col;
        outf[idx] = acc[m][n][r] + bv + residual[idx];
      }
    }
}

// ---------------------------------------------------------------------------
// Flash attention with alibi + causal mask (round-2 proven).
// ---------------------------------------------------------------------------
__global__ __launch_bounds__(256) void attn_fwd(
    const unsigned short* __restrict__ q_bf, const unsigned short* __restrict__ k_bf,
    const unsigned short* __restrict__ v_t, const float* __restrict__ alibi,
    unsigned short* __restrict__ ctx_bf) {
  __shared__ unsigned short Ks[64 * 128];
  __shared__ unsigned short Vs[128 * 64];
  __shared__ unsigned short Ps[4][16 * 64];
  __shared__ float Al[SEQL];

  const int tid = threadIdx.x;
  const int l = tid & 63;
  const int w = tid >> 6;
  const int h = blockIdx.x;
  const int qt = blockIdx.y * 64;
  const int qw = qt + w * 16;

  for (int i = tid; i < SEQL; i += 256) Al[i] = alibi[h * SEQL + i];

  bf16x8 qf[4];
  {
    const unsigned short* qp =
        &q_bf[(long long)(h * SEQL + qw + (l & 15)) * HDIM + (l >> 4) * 8];
#pragma unroll
    for (int kk = 0; kk < 4; ++kk) qf[kk] = *(const bf16x8*)(qp + kk * 32);
  }

  f32x4 oacc[8] = {};
  float mrun[4] = {-__builtin_inff(), -__builtin_inff(), -__builtin_inff(), -__builtin_inff()};
  float lrun[4] = {0.f, 0.f, 0.f, 0.f};
  const float inv_norm = 0.08838834764831845f;

  const int kR = l >> 4, kC = l & 15;
  const int vR = l >> 3, vC = (l & 7) ^ vR;

  const int ntiles = blockIdx.y + 1;
  for (int t = 0; t < ntiles; ++t) {
    const int kv0 = t * 64;
    __syncthreads();
#pragma unroll
    for (int i = 0; i < 4; ++i) {
      const int krow = w * 16 + i * 4 + kR;
      const int ksrc = kC ^ ((i & 1) * 4 + kR);
      gload_lds16(&k_bf[(long long)(h * SEQL + kv0 + krow) * HDIM + ksrc * 8],
                  (char*)Ks + (w * 4 + i) * 1024);
      const int vrow = w * 32 + i * 8 + vR;
      gload_lds16(&v_t[(long long)(h * HDIM + vrow) * SEQL + kv0 + vC * 8],
                  (char*)Vs + (w * 4 + i) * 1024);
    }
    __syncthreads();

    f32x4 sacc[4] = {};
#pragma unroll
    for (int kk = 0; kk < 4; ++kk) {
      const int colb = kk * 64 + (l >> 4) * 16;
#pragma unroll
      for (int n = 0; n < 4; ++n) {
        int row = n * 16 + (l & 15);
        bf16x8 kf = *(const bf16x8*)((char*)Ks + row * 256 + (colb ^ ((row & 7) << 4)));
        sacc[n] = __builtin_amdgcn_mfma_f32_16x16x32_bf16(qf[kk], kf, sacc[n], 0, 0, 0);
      }
    }

    float sc[4][4];
#pragma unroll
    for (int n = 0; n < 4; ++n) {
      const int kv = kv0 + n * 16 + (l & 15);
      const float al = Al[kv];
#pragma unroll
      for (int r = 0; r < 4; ++r) {
        const int qrow = qw + (l >> 4) * 4 + r;
        float v = al + inv_norm * sacc[n][r];
        sc[n][r] = (kv > qrow) ? -__builtin_inff() : v;
      }
    }

#pragma unroll
    for (int r = 0; r < 4; ++r) {
      float m0 = fmaxf(fmaxf(sc[0][r], sc[1][r]), fmaxf(sc[2][r], sc[3][r]));
      m0 = fmaxf(m0, __shfl_xor(m0, 1, 64));
      m0 = fmaxf(m0, __shfl_xor(m0, 2, 64));
      m0 = fmaxf(m0, __shfl_xor(m0, 4, 64));
      m0 = fmaxf(m0, __shfl_xor(m0, 8, 64));
      const float mnew = fmaxf(mrun[r], m0);
      float p0 = 0.f;
#pragma unroll
      for (int n = 0; n < 4; ++n) {
        const float pv = __expf(sc[n][r] - mnew);
        sc[n][r] = pv;
        p0 += pv;
      }
      p0 += __shfl_xor(p0, 1, 64);
      p0 += __shfl_xor(p0, 2, 64);
      p0 += __shfl_xor(p0, 4, 64);
      p0 += __shfl_xor(p0, 8, 64);
      const float scale = __expf(mrun[r] - mnew);
      mrun[r] = mnew;
      lrun[r] = lrun[r] * scale + p0;
#pragma unroll
      for (int n2 = 0; n2 < 8; ++n2) oacc[n2][r] *= scale;
    }

#pragma unroll
    for (int n = 0; n < 4; ++n)
#pragma unroll
      for (int r = 0; r < 4; ++r) {
        const int row = (l >> 4) * 4 + r;
        const int colp = n * 16 + (l & 15);
        *(unsigned short*)((char*)Ps[w] + row * 128 + ((colp * 2) ^ ((row & 7) << 4))) =
            f2bf(sc[n][r]);
      }
    __threadfence_block();
    bf16x8 pf[2];
#pragma unroll
    for (int kk2 = 0; kk2 < 2; ++kk2) {
      const int row = l & 15;
      const int colb = kk2 * 64 + (l >> 4) * 16;
      pf[kk2] = *(const bf16x8*)((char*)Ps[w] + row * 128 + (colb ^ ((row & 7) << 4)));
    }

#pragma unroll
    for (int n2 = 0; n2 < 8; ++n2) {
#pragma unroll
      for (int kk2 = 0; kk2 < 2; ++kk2) {
        const int row = n2 * 16 + (l & 15);
        const int colb = kk2 * 64 + (l >> 4) * 16;
        bf16x8 vf = *(const bf16x8*)((char*)Vs + row * 128 + (colb ^ ((row & 7) << 4)));
        oacc[n2] = __builtin_amdgcn_mfma_f32_16x16x32_bf16(pf[kk2], vf, oacc[n2], 0, 0, 0);
      }
    }
  }

#pragma unroll
  for (int n2 = 0; n2 < 8; ++n2)
#pragma unroll
    for (int r = 0; r < 4; ++r) {
      const int qrow = qw + (l >> 4) * 4 + r;
      const int col = h * HDIM + n2 * 16 + (l & 15);
      ctx_bf[(long long)qrow * HIDN + col] = f2bf(oacc[n2][r] / lrun[r]);
    }
}

extern "C" void kernel_launch(void* const* d_in, const int* in_sizes, int n_in,
                              void* d_out, int out_size, void* d_ws, size_t ws_size,
                              hipStream_t stream) {
  const float* hidden = (const float*)d_in[0];
  const float* residual = (const float*)d_in[1];
  const float* alibi = (const float*)d_in[2];
  // d_in[3]: attention_mask (bool) — causal mask computed analytically
  const float* Wqkv = (const float*)d_in[4];
  const float* bqkv = (const float*)d_in[5];
  const float* Wd = (const float*)d_in[6];
  const float* bd = (const float*)d_in[7];
  float* out = (float*)d_out;

  char* ws = (char*)d_ws;
  const size_t MB16 = 16777216;
  unsigned short* q_bf = (unsigned short*)(ws);
  unsigned short* k_bf = (unsigned short*)(ws + MB16);
  unsigned short* v_t = (unsigned short*)(ws + 2 * MB16);
  unsigned short* hid_bf = (unsigned short*)(ws + 3 * MB16);
  unsigned short* wqkv_bf = (unsigned short*)(ws + 4 * MB16);  // 96 MiB
  unsigned short* wd_bf = (unsigned short*)(ws + 4 * MB16);    // reuse after QKV GEMM
  unsigned short* ctx_bf = (unsigned short*)(ws + 4 * MB16 + 33554432);

  // 1. convert inputs to bf16
  cvt_f32_bf16<<<4096, 256, 0, stream>>>(hidden, hid_bf, (long long)SEQL * HIDN);
  cvt_f32_bf16<<<24576, 256, 0, stream>>>(Wqkv, wqkv_bf, (long long)H3 * HIDN);

  // 2. QKV projection (256^2 8-phase) with interleaved-scatter epilogue
  gemm256_qkv<<<384, 512, 0, stream>>>(hid_bf, wqkv_bf, bqkv, q_bf, k_bf, v_t);

  // 3. convert Wd (reuses Wqkv region — stream-ordered after QKV GEMM)
  cvt_f32_bf16<<<8192, 256, 0, stream>>>(Wd, wd_bf, (long long)HIDN * HIDN);

  // 4. flash attention (alibi + causal)
  attn_fwd<<<dim3(NHEAD, SEQL / 64), 256, 0, stream>>>(q_bf, k_bf, v_t, alibi, ctx_bf);

  // 5. output projection + bias + residual (fp32 out)
  gemm_nt_res<<<dim3(SEQL / 128, HIDN / 128), 256, 0, stream>>>(
      ctx_bf, wd_bf, SEQL, HIDN, HIDN, bd, residual, out);
}

// Round 5
// 496.755 us; speedup vs baseline: 1.0891x; 1.0347x over previous
//
#include <hip/hip_runtime.h>

// BLOOM attention block on MI355X (gfx950).
// GEMMs: proven 128x128 global_load_lds structure (round-2, 838 TF) with
// XCD-bijective block chunking (T1) for L2 locality.
// Attention: flash w/ alibi+causal, longest-first dispatch + XCD head-chunking.
// 8-phase 256^2 attempts (r3/r4) regressed -> reverted per methodology.

#define SEQL 2048
#define HIDN 4096
#define NHEAD 32
#define HDIM 128
#define H3 12288

typedef __bf16 bf16x8 __attribute__((ext_vector_type(8)));
typedef float f32x4 __attribute__((ext_vector_type(4)));
typedef unsigned short u16x8 __attribute__((ext_vector_type(8)));

__device__ __forceinline__ unsigned short f2bf(float f) {
  union { float f; unsigned u; } v; v.f = f;
  return (unsigned short)((v.u + 0x7FFFu + ((v.u >> 16) & 1u)) >> 16);
}

__device__ __forceinline__ void gload_lds16(const void* g, void* l) {
  __builtin_amdgcn_global_load_lds(
      (const __attribute__((address_space(1))) void*)g,
      (__attribute__((address_space(3))) void*)l, 16, 0, 0);
}

__global__ __launch_bounds__(256) void cvt_f32_bf16(
    const float* __restrict__ in, unsigned short* __restrict__ out, long long n) {
  long long i = ((long long)blockIdx.x * blockDim.x + threadIdx.x) * 8;
  long long stride = (long long)gridDim.x * blockDim.x * 8;
  for (; i < n; i += stride) {
    float4 a = *(const float4*)(in + i);
    float4 b = *(const float4*)(in + i + 4);
    u16x8 o;
    o[0] = f2bf(a.x); o[1] = f2bf(a.y); o[2] = f2bf(a.z); o[3] = f2bf(a.w);
    o[4] = f2bf(b.x); o[5] = f2bf(b.y); o[6] = f2bf(b.z); o[7] = f2bf(b.w);
    *(u16x8*)(out + i) = o;
  }
}

// C[M,N] = A[M,K] * B[N,K]^T (+ epilogue). A,B bf16 (ushort bits).
// 128x128 tile, BK=64, 4 waves (2x2 of 64x64), 16x16x32 MFMA, 4x4 frags/wave.
// LDS[r][j16] = G[r][j16^(r&7)] via linear-dest global_load_lds with
// pre-swizzled source chunk (row&7 == lane>>3); reads XOR byte^((r&7)<<4).
// 1-D grid, XCD-bijective chunking: XCD c = b&7 gets contiguous lin chunk
// [c*nb/8, (c+1)*nb/8) = all 16 M-blocks x (Npanels/8) N-panels.
// EPI==0: QKV scatter epilogue (bias + write q/k/v_t as bf16).
// EPI==1: out = acc + bias[col] + residual[row*N+col], fp32.
template <int EPI>
__global__ __launch_bounds__(256) void gemm_nt(
    const unsigned short* __restrict__ A, const unsigned short* __restrict__ B,
    int M, int N, int K,
    const float* __restrict__ bias, const float* __restrict__ residual,
    float* __restrict__ outf,
    unsigned short* __restrict__ q_bf, unsigned short* __restrict__ k_bf,
    unsigned short* __restrict__ v_t) {
  __shared__ unsigned short As[128 * 64];  // 16 KiB
  __shared__ unsigned short Bs[128 * 64];  // 16 KiB

  const int tid = threadIdx.x;
  const int l = tid & 63;
  const int w = tid >> 6;
  const int wr = (w >> 1) * 64;   // wave row offset in tile
  const int wc = (w & 1) * 64;    // wave col offset in tile

  // XCD-bijective remap (nb = gridDim.x, multiple of 8; M/128 = 16).
  const int nb = gridDim.x;
  const int lin = (blockIdx.x & 7) * (nb >> 3) + (blockIdx.x >> 3);
  const int tm0 = (lin & 15) * 128;
  const int tn0 = (lin >> 4) * 128;

  const int lr = l >> 3;          // staging row-in-chunk
  const int lc = (l & 7) ^ lr;    // pre-swizzled 16B source chunk

  f32x4 acc[4][4] = {};

  for (int kt = 0; kt < K; kt += 64) {
    __syncthreads();
#pragma unroll
    for (int i = 0; i < 4; ++i) {
      const int row = w * 32 + i * 8 + lr;
      gload_lds16(&A[(long long)(tm0 + row) * K + kt + lc * 8],
                  (char*)As + (w * 4 + i) * 1024);
      gload_lds16(&B[(long long)(tn0 + row) * K + kt + lc * 8],
                  (char*)Bs + (w * 4 + i) * 1024);
    }
    __syncthreads();
#pragma unroll
    for (int kk = 0; kk < 2; ++kk) {
      const int colb = kk * 64 + (l >> 4) * 16;  // byte offset in row
      bf16x8 af[4], bfr[4];
#pragma unroll
      for (int m = 0; m < 4; ++m) {
        int row = wr + m * 16 + (l & 15);
        af[m] = *(const bf16x8*)((char*)As + row * 128 + (colb ^ ((row & 7) << 4)));
      }
#pragma unroll
      for (int n = 0; n < 4; ++n) {
        int row = wc + n * 16 + (l & 15);
        bfr[n] = *(const bf16x8*)((char*)Bs + row * 128 + (colb ^ ((row & 7) << 4)));
      }
#pragma unroll
      for (int m = 0; m < 4; ++m)
#pragma unroll
        for (int n = 0; n < 4; ++n)
          acc[m][n] = __builtin_amdgcn_mfma_f32_16x16x32_bf16(af[m], bfr[n], acc[m][n], 0, 0, 0);
    }
  }

  // Epilogue. D layout: col = lane&15, row = (lane>>4)*4 + reg (m89-verified).
#pragma unroll
  for (int m = 0; m < 4; ++m) {
#pragma unroll
    for (int n = 0; n < 4; ++n) {
      const int col = tn0 + wc + n * 16 + (l & 15);
      const float bv = bias[col];
#pragma unroll
      for (int r = 0; r < 4; ++r) {
        const int rowg = tm0 + wr + m * 16 + (l >> 4) * 4 + r;
        float v = acc[m][n][r] + bv;
        if (EPI == 0) {
          // fused[s, head*384 + which*128 + d]
          const int head = col / 384;
          const int rem = col - head * 384;
          const int which = rem >> 7;
          const int d = rem & 127;
          const unsigned short bv16 = f2bf(v);
          if (which == 0)
            q_bf[(long long)(head * SEQL + rowg) * HDIM + d] = bv16;
          else if (which == 1)
            k_bf[(long long)(head * SEQL + rowg) * HDIM + d] = bv16;
          else
            v_t[(long long)(head * HDIM + d) * SEQL + rowg] = bv16;
        } else {
          const long long idx = (long long)rowg * N + col;
          outf[idx] = v + residual[idx];
        }
      }
    }
  }
}

// Flash attention with alibi + causal mask.
// 1-D grid of 1024 blocks. XCD c = b&7 owns heads [4c,4c+4) (KV set ~4MB ~ L2);
// q-tiles dispatched longest-first within each XCD for tail packing.
// Block: one head x 64 q rows. 4 waves, each owns 16 q rows. KV tiles of 64.
__global__ __launch_bounds__(256) void attn_fwd(
    const unsigned short* __restrict__ q_bf, const unsigned short* __restrict__ k_bf,
    const unsigned short* __restrict__ v_t, const float* __restrict__ alibi,
    unsigned short* __restrict__ ctx_bf) {
  __shared__ unsigned short Ks[64 * 128];   // 16 KiB (rows = kv, 256B/row)
  __shared__ unsigned short Vs[128 * 64];   // 16 KiB (rows = d, 128B/row)
  __shared__ unsigned short Ps[4][16 * 64]; // 8 KiB  (per-wave P tile)
  __shared__ float Al[SEQL];                // 8 KiB  (alibi row for this head)

  const int tid = threadIdx.x;
  const int l = tid & 63;
  const int w = tid >> 6;

  // remap: b -> (head, qtile). xcd = b&7; i = b>>3 in [0,128);
  // head = xcd*4 + (i&3); qtile = 31 - (i>>2)  (longest first).
  const int b = blockIdx.x;
  const int i_ = b >> 3;
  const int h = (b & 7) * 4 + (i_ & 3);
  const int qtile = 31 - (i_ >> 2);
  const int qw = qtile * 64 + w * 16;  // this wave's q-row base

  for (int i = tid; i < SEQL; i += 256) Al[i] = alibi[h * SEQL + i];

  // Q fragments: lane l holds row qw+(l&15), cols kk*32+(l>>4)*8..+7
  bf16x8 qf[4];
  {
    const unsigned short* qp =
        &q_bf[(long long)(h * SEQL + qw + (l & 15)) * HDIM + (l >> 4) * 8];
#pragma unroll
    for (int kk = 0; kk < 4; ++kk) qf[kk] = *(const bf16x8*)(qp + kk * 32);
  }

  f32x4 oacc[8] = {};
  float mrun[4] = {-__builtin_inff(), -__builtin_inff(), -__builtin_inff(), -__builtin_inff()};
  float lrun[4] = {0.f, 0.f, 0.f, 0.f};
  const float inv_norm = 0.08838834764831845f;  // 1/sqrt(128)

  const int kR = l >> 4, kC = l & 15;
  const int vR = l >> 3, vC = (l & 7) ^ vR;

  const int ntiles = qtile + 1;  // causal
  for (int t = 0; t < ntiles; ++t) {
    const int kv0 = t * 64;
    __syncthreads();
#pragma unroll
    for (int i = 0; i < 4; ++i) {
      const int krow = w * 16 + i * 4 + kR;
      const int ksrc = kC ^ ((i & 1) * 4 + kR);
      gload_lds16(&k_bf[(long long)(h * SEQL + kv0 + krow) * HDIM + ksrc * 8],
                  (char*)Ks + (w * 4 + i) * 1024);
      const int vrow = w * 32 + i * 8 + vR;
      gload_lds16(&v_t[(long long)(h * HDIM + vrow) * SEQL + kv0 + vC * 8],
                  (char*)Vs + (w * 4 + i) * 1024);
    }
    __syncthreads();

    f32x4 sacc[4] = {};
#pragma unroll
    for (int kk = 0; kk < 4; ++kk) {
      const int colb = kk * 64 + (l >> 4) * 16;
#pragma unroll
      for (int n = 0; n < 4; ++n) {
        int row = n * 16 + (l & 15);
        bf16x8 kf = *(const bf16x8*)((char*)Ks + row * 256 + (colb ^ ((row & 7) << 4)));
        sacc[n] = __builtin_amdgcn_mfma_f32_16x16x32_bf16(qf[kk], kf, sacc[n], 0, 0, 0);
      }
    }

    float sc[4][4];
#pragma unroll
    for (int n = 0; n < 4; ++n) {
      const int kv = kv0 + n * 16 + (l & 15);
      const float al = Al[kv];
#pragma unroll
      for (int r = 0; r < 4; ++r) {
        const int qrow = qw + (l >> 4) * 4 + r;
        float v = al + inv_norm * sacc[n][r];
        sc[n][r] = (kv > qrow) ? -__builtin_inff() : v;
      }
    }

#pragma unroll
    for (int r = 0; r < 4; ++r) {
      float m0 = fmaxf(fmaxf(sc[0][r], sc[1][r]), fmaxf(sc[2][r], sc[3][r]));
      m0 = fmaxf(m0, __shfl_xor(m0, 1, 64));
      m0 = fmaxf(m0, __shfl_xor(m0, 2, 64));
      m0 = fmaxf(m0, __shfl_xor(m0, 4, 64));
      m0 = fmaxf(m0, __shfl_xor(m0, 8, 64));
      const float mnew = fmaxf(mrun[r], m0);
      float p0 = 0.f;
#pragma unroll
      for (int n = 0; n < 4; ++n) {
        const float pv = __expf(sc[n][r] - mnew);
        sc[n][r] = pv;
        p0 += pv;
      }
      p0 += __shfl_xor(p0, 1, 64);
      p0 += __shfl_xor(p0, 2, 64);
      p0 += __shfl_xor(p0, 4, 64);
      p0 += __shfl_xor(p0, 8, 64);
      const float scale = __expf(mrun[r] - mnew);
      mrun[r] = mnew;
      lrun[r] = lrun[r] * scale + p0;
#pragma unroll
      for (int n2 = 0; n2 < 8; ++n2) oacc[n2][r] *= scale;
    }

#pragma unroll
    for (int n = 0; n < 4; ++n)
#pragma unroll
      for (int r = 0; r < 4; ++r) {
        const int row = (l >> 4) * 4 + r;
        const int colp = n * 16 + (l & 15);
        *(unsigned short*)((char*)Ps[w] + row * 128 + ((colp * 2) ^ ((row & 7) << 4))) =
            f2bf(sc[n][r]);
      }
    __threadfence_block();
    bf16x8 pf[2];
#pragma unroll
    for (int kk2 = 0; kk2 < 2; ++kk2) {
      const int row = l & 15;
      const int colb = kk2 * 64 + (l >> 4) * 16;
      pf[kk2] = *(const bf16x8*)((char*)Ps[w] + row * 128 + (colb ^ ((row & 7) << 4)));
    }

#pragma unroll
    for (int n2 = 0; n2 < 8; ++n2) {
#pragma unroll
      for (int kk2 = 0; kk2 < 2; ++kk2) {
        const int row = n2 * 16 + (l & 15);
        const int colb = kk2 * 64 + (l >> 4) * 16;
        bf16x8 vf = *(const bf16x8*)((char*)Vs + row * 128 + (colb ^ ((row & 7) << 4)));
        oacc[n2] = __builtin_amdgcn_mfma_f32_16x16x32_bf16(pf[kk2], vf, oacc[n2], 0, 0, 0);
      }
    }
  }

#pragma unroll
  for (int n2 = 0; n2 < 8; ++n2)
#pragma unroll
    for (int r = 0; r < 4; ++r) {
      const int qrow = qw + (l >> 4) * 4 + r;
      const int col = h * HDIM + n2 * 16 + (l & 15);
      ctx_bf[(long long)qrow * HIDN + col] = f2bf(oacc[n2][r] / lrun[r]);
    }
}

extern "C" void kernel_launch(void* const* d_in, const int* in_sizes, int n_in,
                              void* d_out, int out_size, void* d_ws, size_t ws_size,
                              hipStream_t stream) {
  const float* hidden = (const float*)d_in[0];
  const float* residual = (const float*)d_in[1];
  const float* alibi = (const float*)d_in[2];
  // d_in[3]: attention_mask (bool) — causal mask computed analytically
  const float* Wqkv = (const float*)d_in[4];
  const float* bqkv = (const float*)d_in[5];
  const float* Wd = (const float*)d_in[6];
  const float* bd = (const float*)d_in[7];
  float* out = (float*)d_out;

  char* ws = (char*)d_ws;
  const size_t MB16 = 16777216;
  unsigned short* q_bf = (unsigned short*)(ws);
  unsigned short* k_bf = (unsigned short*)(ws + MB16);
  unsigned short* v_t = (unsigned short*)(ws + 2 * MB16);
  unsigned short* hid_bf = (unsigned short*)(ws + 3 * MB16);
  unsigned short* wqkv_bf = (unsigned short*)(ws + 4 * MB16);  // 96 MiB
  unsigned short* wd_bf = (unsigned short*)(ws + 4 * MB16);    // reuse after QKV GEMM
  unsigned short* ctx_bf = (unsigned short*)(ws + 4 * MB16 + 33554432);

  // 1. convert inputs to bf16
  cvt_f32_bf16<<<4096, 256, 0, stream>>>(hidden, hid_bf, (long long)SEQL * HIDN);
  cvt_f32_bf16<<<24576, 256, 0, stream>>>(Wqkv, wqkv_bf, (long long)H3 * HIDN);

  // 2. QKV projection (128^2, XCD-chunked) with interleaved-scatter epilogue
  gemm_nt<0><<<(SEQL / 128) * (H3 / 128), 256, 0, stream>>>(
      hid_bf, wqkv_bf, SEQL, H3, HIDN, bqkv, nullptr, nullptr, q_bf, k_bf, v_t);

  // 3. convert Wd (reuses Wqkv region — stream-ordered after QKV GEMM)
  cvt_f32_bf16<<<8192, 256, 0, stream>>>(Wd, wd_bf, (long long)HIDN * HIDN);

  // 4. flash attention (alibi + causal), longest-first + XCD head-chunking
  attn_fwd<<<NHEAD * (SEQL / 64), 256, 0, stream>>>(q_bf, k_bf, v_t, alibi, ctx_bf);

  // 5. output projection + bias + residual (fp32 out)
  gemm_nt<1><<<(SEQL / 128) * (HIDN / 128), 256, 0, stream>>>(
      ctx_bf, wd_bf, SEQL, HIDN, HIDN, bd, residual, out, nullptr, nullptr, nullptr);
}

// Round 6
// 491.232 us; speedup vs baseline: 1.1013x; 1.0112x over previous
//
#include <hip/hip_runtime.h>

// BLOOM attention block on MI355X (gfx950).
// QKV GEMM: 256x256 8-phase template with BLOCK-level quadrants (the r3/r4
// ports used per-wave quadrants -> every phase touched all LDS halves ->
// forced shallow prefetch; fixed here). Counted vmcnt(4) twice per K-tile,
// pure-MFMA windows, setprio, XCD-bijective map.
// Final GEMM + attention: proven round-5 structure.

#define SEQL 2048
#define HIDN 4096
#define NHEAD 32
#define HDIM 128
#define H3 12288

typedef __bf16 bf16x8 __attribute__((ext_vector_type(8)));
typedef float f32x4 __attribute__((ext_vector_type(4)));
typedef unsigned short u16x8 __attribute__((ext_vector_type(8)));

__device__ __forceinline__ unsigned short f2bf(float f) {
  union { float f; unsigned u; } v; v.f = f;
  return (unsigned short)((v.u + 0x7FFFu + ((v.u >> 16) & 1u)) >> 16);
}

__device__ __forceinline__ void gload_lds16(const void* g, void* l) {
  __builtin_amdgcn_global_load_lds(
      (const __attribute__((address_space(1))) void*)g,
      (__attribute__((address_space(3))) void*)l, 16, 0, 0);
}

#define BAR() __builtin_amdgcn_s_barrier()
#define SB0() __builtin_amdgcn_sched_barrier(0)
#define VMW(n) asm volatile("s_waitcnt vmcnt(" #n ")" ::: "memory")
#define LGKM(n) asm volatile("s_waitcnt lgkmcnt(" #n ")" ::: "memory")

__global__ __launch_bounds__(256) void cvt_f32_bf16(
    const float* __restrict__ in, unsigned short* __restrict__ out, long long n) {
  long long i = ((long long)blockIdx.x * blockDim.x + threadIdx.x) * 8;
  long long stride = (long long)gridDim.x * blockDim.x * 8;
  for (; i < n; i += stride) {
    float4 a = *(const float4*)(in + i);
    float4 b = *(const float4*)(in + i + 4);
    u16x8 o;
    o[0] = f2bf(a.x); o[1] = f2bf(a.y); o[2] = f2bf(a.z); o[3] = f2bf(a.w);
    o[4] = f2bf(b.x); o[5] = f2bf(b.y); o[6] = f2bf(b.z); o[7] = f2bf(b.w);
    *(u16x8*)(out + i) = o;
  }
}

// ---------------------------------------------------------------------------
// 256x256 8-phase QKV GEMM. C[2048,12288] = A * B^T, K=4096, BK=64.
// 8 waves as 2x4 over each BLOCK quadrant (mh,nh) = 128x128 of C.
// Phase (mh,nh) reads ONLY A-half mh + B-half nh. Quadrant order
// (0,0),(0,1),(1,1),(1,0): A0 free after ph2, B1 after ph3, A1/B0 after ph4
// (even tile, buf0; odd tile phases 5-8, buf1).
// Stage slots (tiles a=2j buf0, b=2j+1 buf1, c=2j+2, d=2j+3):
//   ph1: b.B0  ph2: b.A1  ph3: c.A0  ph4: c.B1  ph5: c.A1 + c.B0
//   ph7: d.A0  ph8: d.B1
// vmcnt(4)@ph4: confirms {b.A0,b.B1(older), b.B0@1, b.A1@2} for ph5-7 reads.
// vmcnt(4)@ph8: confirms {c.A0@3, c.B1@4, c.A1/c.B0@5} for next ph1-3 reads.
// WAR: every stage lands >=1 barrier after its half's last read (see order).
// Last iter: S3+ guarded off; vmcnt(0)@ph4 drains.
// ---------------------------------------------------------------------------
__global__ __launch_bounds__(512, 2) void gemm256_qkv(
    const unsigned short* __restrict__ A, const unsigned short* __restrict__ B,
    const float* __restrict__ bias,
    unsigned short* __restrict__ q_bf, unsigned short* __restrict__ k_bf,
    unsigned short* __restrict__ v_t) {
  __shared__ unsigned short Ab[2][2][8192];  // [buf][half][128*64]
  __shared__ unsigned short Bb[2][2][8192];

  const int tid = threadIdx.x;
  const int l = tid & 63;
  const int w = tid >> 6;
  const int K = HIDN;

  // XCD-bijective: 384 = 8 XCD * 48; XCD c owns N-panels [6c,6c+6) x all M.
  const int b = blockIdx.x;
  const int lin = (b & 7) * 48 + (b >> 3);
  const int tm0 = (lin & 7) * 256;
  const int tn0 = (lin >> 3) * 256;

  const int lr = l >> 3;          // staging row-in-8-row-chunk
  const int lc = (l & 7) ^ lr;    // pre-swizzled source 16B chunk
  const int wr2 = w >> 2;         // wave row in quadrant (0/1 -> 64 rows)
  const int wc2 = w & 3;          // wave col in quadrant (0..3 -> 32 cols)

  f32x4 acc[2][2][4][2] = {};     // [mh][nh][mi][ni]
  bf16x8 A0s[4][2], A1s[4][2], B0s[2][2], B1s[2][2];

  auto stA = [&](int tt, int h) {
#pragma unroll
    for (int i = 0; i < 2; ++i) {
      const int c = w * 2 + i;    // 1KB chunk = 8 rows
      gload_lds16(&A[(long long)(tm0 + h * 128 + c * 8 + lr) * K + tt * 64 + lc * 8],
                  (char*)&Ab[tt & 1][h][0] + c * 1024);
    }
  };
  auto stB = [&](int tt, int h) {
#pragma unroll
    for (int i = 0; i < 2; ++i) {
      const int c = w * 2 + i;
      gload_lds16(&B[(long long)(tn0 + h * 128 + c * 8 + lr) * K + tt * 64 + lc * 8],
                  (char*)&Bb[tt & 1][h][0] + c * 1024);
    }
  };
  auto rdA = [&](bf16x8 (&dst)[4][2], int bufi, int h) {
#pragma unroll
    for (int mi = 0; mi < 4; ++mi) {
      const int r = wr2 * 64 + mi * 16 + (l & 15);
#pragma unroll
      for (int kk = 0; kk < 2; ++kk)
        dst[mi][kk] = *(const bf16x8*)((const char*)&Ab[bufi][h][0] +
            r * 128 + ((kk * 64 + (l >> 4) * 16) ^ ((r & 7) << 4)));
    }
  };
  auto rdB = [&](bf16x8 (&dst)[2][2], int bufi, int h) {
#pragma unroll
    for (int ni = 0; ni < 2; ++ni) {
      const int r = wc2 * 32 + ni * 16 + (l & 15);
#pragma unroll
      for (int kk = 0; kk < 2; ++kk)
        dst[ni][kk] = *(const bf16x8*)((const char*)&Bb[bufi][h][0] +
            r * 128 + ((kk * 64 + (l >> 4) * 16) ^ ((r & 7) << 4)));
    }
  };

#define MFMA16(As_, Bs_, mh_, nh_)                                            \
  __builtin_amdgcn_s_setprio(1);                                              \
  _Pragma("unroll") for (int kk = 0; kk < 2; ++kk)                            \
    _Pragma("unroll") for (int mi = 0; mi < 4; ++mi)                          \
      _Pragma("unroll") for (int ni = 0; ni < 2; ++ni)                        \
        acc[mh_][nh_][mi][ni] = __builtin_amdgcn_mfma_f32_16x16x32_bf16(      \
            As_[mi][kk], Bs_[ni][kk], acc[mh_][nh_][mi][ni], 0, 0, 0);        \
  __builtin_amdgcn_s_setprio(0);

  // Prologue: tile0 all halves + tile1 {A0, B1}; confirm tile0.
  stA(0, 0); stB(0, 0); stB(0, 1); stA(0, 1);
  stA(1, 0); stB(1, 1);
  VMW(4);           // confirms tile0's 4 halves
  BAR();

  const int NT = K / 64;       // 64
  const int NITER = NT / 2;    // 32
  for (int j = 0; j < NITER; ++j) {
    const int bT = 2 * j + 1, c = 2 * j + 2, dT = 2 * j + 3;
    const bool g = (j + 1) < NITER;
    // ---- ph1: reads A0,B0(buf0); stage b.B0 ----
    rdA(A0s, 0, 0);
    rdB(B0s, 0, 0);
    stB(bT, 0);
    LGKM(8);
    SB0(); BAR();
    LGKM(0); SB0();
    MFMA16(A0s, B0s, 0, 0);
    SB0(); BAR();
    // ---- ph2: reads B1(buf0); stage b.A1 ----
    rdB(B1s, 0, 1);
    stA(bT, 1);
    SB0(); BAR();
    LGKM(0); SB0();
    MFMA16(A0s, B1s, 0, 1);
    SB0(); BAR();
    // ---- ph3: reads A1(buf0); stage c.A0 ----
    rdA(A1s, 0, 1);
    if (g) stA(c, 0);
    SB0(); BAR();
    LGKM(0); SB0();
    MFMA16(A1s, B1s, 1, 1);
    SB0(); BAR();
    // ---- ph4: stage c.B1; counted wait ----
    if (g) { stB(c, 1); VMW(4); } else { VMW(0); }
    SB0(); BAR();
    MFMA16(A1s, B0s, 1, 0);
    SB0(); BAR();
    // ---- ph5: reads A0,B0(buf1); stage c.A1 + c.B0 ----
    rdA(A0s, 1, 0);
    rdB(B0s, 1, 0);
    if (g) { stA(c, 1); stB(c, 0); }
    LGKM(8);
    SB0(); BAR();
    LGKM(0); SB0();
    MFMA16(A0s, B0s, 0, 0);
    SB0(); BAR();
    // ---- ph6: reads B1(buf1) ----
    rdB(B1s, 1, 1);
    SB0(); BAR();
    LGKM(0); SB0();
    MFMA16(A0s, B1s, 0, 1);
    SB0(); BAR();
    // ---- ph7: reads A1(buf1); stage d.A0 ----
    rdA(A1s, 1, 1);
    if (g) stA(dT, 0);
    SB0(); BAR();
    LGKM(0); SB0();
    MFMA16(A1s, B1s, 1, 1);
    SB0(); BAR();
    // ---- ph8: stage d.B1; counted wait ----
    if (g) { stB(dT, 1); VMW(4); }
    SB0(); BAR();
    MFMA16(A1s, B0s, 1, 0);
    SB0(); BAR();
  }

  // Epilogue: bias + interleaved QKV scatter. D: col=lane&15, row=(l>>4)*4+r.
#pragma unroll
  for (int mh = 0; mh < 2; ++mh)
#pragma unroll
    for (int nh = 0; nh < 2; ++nh)
#pragma unroll
      for (int mi = 0; mi < 4; ++mi)
#pragma unroll
        for (int ni = 0; ni < 2; ++ni) {
          const int col = tn0 + nh * 128 + wc2 * 32 + ni * 16 + (l & 15);
          const float bv = bias[col];
          const int head = col / 384;
          const int rem = col - head * 384;
          const int which = rem >> 7;
          const int d = rem & 127;
#pragma unroll
          for (int r = 0; r < 4; ++r) {
            const int row = tm0 + mh * 128 + wr2 * 64 + mi * 16 + (l >> 4) * 4 + r;
            const unsigned short bv16 = f2bf(acc[mh][nh][mi][ni][r] + bv);
            if (which == 0)
              q_bf[(long long)(head * SEQL + row) * HDIM + d] = bv16;
            else if (which == 1)
              k_bf[(long long)(head * SEQL + row) * HDIM + d] = bv16;
            else
              v_t[(long long)(head * HDIM + d) * SEQL + row] = bv16;
          }
        }
}

// ---------------------------------------------------------------------------
// 128x128 GEMM (proven) — output projection + bias + residual, XCD-chunked.
// ---------------------------------------------------------------------------
__global__ __launch_bounds__(256) void gemm_nt_res(
    const unsigned short* __restrict__ A, const unsigned short* __restrict__ B,
    int M, int N, int K,
    const float* __restrict__ bias, const float* __restrict__ residual,
    float* __restrict__ outf) {
  __shared__ unsigned short As[128 * 64];
  __shared__ unsigned short Bs[128 * 64];

  const int tid = threadIdx.x;
  const int l = tid & 63;
  const int w = tid >> 6;
  const int wr = (w >> 1) * 64;
  const int wc = (w & 1) * 64;

  const int nb = gridDim.x;
  const int lin = (blockIdx.x & 7) * (nb >> 3) + (blockIdx.x >> 3);
  const int tm0 = (lin & 15) * 128;
  const int tn0 = (lin >> 4) * 128;

  const int lr = l >> 3;
  const int lc = (l & 7) ^ lr;

  f32x4 acc[4][4] = {};

  for (int kt = 0; kt < K; kt += 64) {
    __syncthreads();
#pragma unroll
    for (int i = 0; i < 4; ++i) {
      const int row = w * 32 + i * 8 + lr;
      gload_lds16(&A[(long long)(tm0 + row) * K + kt + lc * 8],
                  (char*)As + (w * 4 + i) * 1024);
      gload_lds16(&B[(long long)(tn0 + row) * K + kt + lc * 8],
                  (char*)Bs + (w * 4 + i) * 1024);
    }
    __syncthreads();
#pragma unroll
    for (int kk = 0; kk < 2; ++kk) {
      const int colb = kk * 64 + (l >> 4) * 16;
      bf16x8 af[4], bfr[4];
#pragma unroll
      for (int m = 0; m < 4; ++m) {
        int row = wr + m * 16 + (l & 15);
        af[m] = *(const bf16x8*)((char*)As + row * 128 + (colb ^ ((row & 7) << 4)));
      }
#pragma unroll
      for (int n = 0; n < 4; ++n) {
        int row = wc + n * 16 + (l & 15);
        bfr[n] = *(const bf16x8*)((char*)Bs + row * 128 + (colb ^ ((row & 7) << 4)));
      }
#pragma unroll
      for (int m = 0; m < 4; ++m)
#pragma unroll
        for (int n = 0; n < 4; ++n)
          acc[m][n] = __builtin_amdgcn_mfma_f32_16x16x32_bf16(af[m], bfr[n], acc[m][n], 0, 0, 0);
    }
  }

#pragma unroll
  for (int m = 0; m < 4; ++m)
#pragma unroll
    for (int n = 0; n < 4; ++n) {
      const int col = tn0 + wc + n * 16 + (l & 15);
      const float bv = bias[col];
#pragma unroll
      for (int r = 0; r < 4; ++r) {
        const int rowg = tm0 + wr + m * 16 + (l >> 4) * 4 + r;
        const long long idx = (long long)rowg * N + col;
        outf[idx] = acc[m][n][r] + bv + residual[idx];
      }
    }
}

// ---------------------------------------------------------------------------
// Flash attention with alibi + causal mask (round-5 proven).
// ---------------------------------------------------------------------------
__global__ __launch_bounds__(256) void attn_fwd(
    const unsigned short* __restrict__ q_bf, const unsigned short* __restrict__ k_bf,
    const unsigned short* __restrict__ v_t, const float* __restrict__ alibi,
    unsigned short* __restrict__ ctx_bf) {
  __shared__ unsigned short Ks[64 * 128];
  __shared__ unsigned short Vs[128 * 64];
  __shared__ unsigned short Ps[4][16 * 64];
  __shared__ float Al[SEQL];

  const int tid = threadIdx.x;
  const int l = tid & 63;
  const int w = tid >> 6;

  const int b = blockIdx.x;
  const int i_ = b >> 3;
  const int h = (b & 7) * 4 + (i_ & 3);
  const int qtile = 31 - (i_ >> 2);
  const int qw = qtile * 64 + w * 16;

  for (int i = tid; i < SEQL; i += 256) Al[i] = alibi[h * SEQL + i];

  bf16x8 qf[4];
  {
    const unsigned short* qp =
        &q_bf[(long long)(h * SEQL + qw + (l & 15)) * HDIM + (l >> 4) * 8];
#pragma unroll
    for (int kk = 0; kk < 4; ++kk) qf[kk] = *(const bf16x8*)(qp + kk * 32);
  }

  f32x4 oacc[8] = {};
  float mrun[4] = {-__builtin_inff(), -__builtin_inff(), -__builtin_inff(), -__builtin_inff()};
  float lrun[4] = {0.f, 0.f, 0.f, 0.f};
  const float inv_norm = 0.08838834764831845f;

  const int kR = l >> 4, kC = l & 15;
  const int vR = l >> 3, vC = (l & 7) ^ vR;

  const int ntiles = qtile + 1;
  for (int t = 0; t < ntiles; ++t) {
    const int kv0 = t * 64;
    __syncthreads();
#pragma unroll
    for (int i = 0; i < 4; ++i) {
      const int krow = w * 16 + i * 4 + kR;
      const int ksrc = kC ^ ((i & 1) * 4 + kR);
      gload_lds16(&k_bf[(long long)(h * SEQL + kv0 + krow) * HDIM + ksrc * 8],
                  (char*)Ks + (w * 4 + i) * 1024);
      const int vrow = w * 32 + i * 8 + vR;
      gload_lds16(&v_t[(long long)(h * HDIM + vrow) * SEQL + kv0 + vC * 8],
                  (char*)Vs + (w * 4 + i) * 1024);
    }
    __syncthreads();

    f32x4 sacc[4] = {};
#pragma unroll
    for (int kk = 0; kk < 4; ++kk) {
      const int colb = kk * 64 + (l >> 4) * 16;
#pragma unroll
      for (int n = 0; n < 4; ++n) {
        int row = n * 16 + (l & 15);
        bf16x8 kf = *(const bf16x8*)((char*)Ks + row * 256 + (colb ^ ((row & 7) << 4)));
        sacc[n] = __builtin_amdgcn_mfma_f32_16x16x32_bf16(qf[kk], kf, sacc[n], 0, 0, 0);
      }
    }

    float sc[4][4];
#pragma unroll
    for (int n = 0; n < 4; ++n) {
      const int kv = kv0 + n * 16 + (l & 15);
      const float al = Al[kv];
#pragma unroll
      for (int r = 0; r < 4; ++r) {
        const int qrow = qw + (l >> 4) * 4 + r;
        float v = al + inv_norm * sacc[n][r];
        sc[n][r] = (kv > qrow) ? -__builtin_inff() : v;
      }
    }

#pragma unroll
    for (int r = 0; r < 4; ++r) {
      float m0 = fmaxf(fmaxf(sc[0][r], sc[1][r]), fmaxf(sc[2][r], sc[3][r]));
      m0 = fmaxf(m0, __shfl_xor(m0, 1, 64));
      m0 = fmaxf(m0, __shfl_xor(m0, 2, 64));
      m0 = fmaxf(m0, __shfl_xor(m0, 4, 64));
      m0 = fmaxf(m0, __shfl_xor(m0, 8, 64));
      const float mnew = fmaxf(mrun[r], m0);
      float p0 = 0.f;
#pragma unroll
      for (int n = 0; n < 4; ++n) {
        const float pv = __expf(sc[n][r] - mnew);
        sc[n][r] = pv;
        p0 += pv;
      }
      p0 += __shfl_xor(p0, 1, 64);
      p0 += __shfl_xor(p0, 2, 64);
      p0 += __shfl_xor(p0, 4, 64);
      p0 += __shfl_xor(p0, 8, 64);
      const float scale = __expf(mrun[r] - mnew);
      mrun[r] = mnew;
      lrun[r] = lrun[r] * scale + p0;
#pragma unroll
      for (int n2 = 0; n2 < 8; ++n2) oacc[n2][r] *= scale;
    }

#pragma unroll
    for (int n = 0; n < 4; ++n)
#pragma unroll
      for (int r = 0; r < 4; ++r) {
        const int row = (l >> 4) * 4 + r;
        const int colp = n * 16 + (l & 15);
        *(unsigned short*)((char*)Ps[w] + row * 128 + ((colp * 2) ^ ((row & 7) << 4))) =
            f2bf(sc[n][r]);
      }
    __threadfence_block();
    bf16x8 pf[2];
#pragma unroll
    for (int kk2 = 0; kk2 < 2; ++kk2) {
      const int row = l & 15;
      const int colb = kk2 * 64 + (l >> 4) * 16;
      pf[kk2] = *(const bf16x8*)((char*)Ps[w] + row * 128 + (colb ^ ((row & 7) << 4)));
    }

#pragma unroll
    for (int n2 = 0; n2 < 8; ++n2) {
#pragma unroll
      for (int kk2 = 0; kk2 < 2; ++kk2) {
        const int row = n2 * 16 + (l & 15);
        const int colb = kk2 * 64 + (l >> 4) * 16;
        bf16x8 vf = *(const bf16x8*)((char*)Vs + row * 128 + (colb ^ ((row & 7) << 4)));
        oacc[n2] = __builtin_amdgcn_mfma_f32_16x16x32_bf16(pf[kk2], vf, oacc[n2], 0, 0, 0);
      }
    }
  }

#pragma unroll
  for (int n2 = 0; n2 < 8; ++n2)
#pragma unroll
    for (int r = 0; r < 4; ++r) {
      const int qrow = qw + (l >> 4) * 4 + r;
      const int col = h * HDIM + n2 * 16 + (l & 15);
      ctx_bf[(long long)qrow * HIDN + col] = f2bf(oacc[n2][r] / lrun[r]);
    }
}

extern "C" void kernel_launch(void* const* d_in, const int* in_sizes, int n_in,
                              void* d_out, int out_size, void* d_ws, size_t ws_size,
                              hipStream_t stream) {
  const float* hidden = (const float*)d_in[0];
  const float* residual = (const float*)d_in[1];
  const float* alibi = (const float*)d_in[2];
  // d_in[3]: attention_mask (bool) — causal mask computed analytically
  const float* Wqkv = (const float*)d_in[4];
  const float* bqkv = (const float*)d_in[5];
  const float* Wd = (const float*)d_in[6];
  const float* bd = (const float*)d_in[7];
  float* out = (float*)d_out;

  char* ws = (char*)d_ws;
  const size_t MB16 = 16777216;
  unsigned short* q_bf = (unsigned short*)(ws);
  unsigned short* k_bf = (unsigned short*)(ws + MB16);
  unsigned short* v_t = (unsigned short*)(ws + 2 * MB16);
  unsigned short* hid_bf = (unsigned short*)(ws + 3 * MB16);
  unsigned short* wqkv_bf = (unsigned short*)(ws + 4 * MB16);  // 96 MiB
  unsigned short* wd_bf = (unsigned short*)(ws + 4 * MB16);    // reuse after QKV GEMM
  unsigned short* ctx_bf = (unsigned short*)(ws + 4 * MB16 + 33554432);

  // 1. convert inputs to bf16
  cvt_f32_bf16<<<4096, 256, 0, stream>>>(hidden, hid_bf, (long long)SEQL * HIDN);
  cvt_f32_bf16<<<24576, 256, 0, stream>>>(Wqkv, wqkv_bf, (long long)H3 * HIDN);

  // 2. QKV projection (256^2 8-phase, block-quadrant) + QKV scatter epilogue
  gemm256_qkv<<<384, 512, 0, stream>>>(hid_bf, wqkv_bf, bqkv, q_bf, k_bf, v_t);

  // 3. convert Wd (reuses Wqkv region — stream-ordered after QKV GEMM)
  cvt_f32_bf16<<<8192, 256, 0, stream>>>(Wd, wd_bf, (long long)HIDN * HIDN);

  // 4. flash attention (alibi + causal), longest-first + XCD head-chunking
  attn_fwd<<<NHEAD * (SEQL / 64), 256, 0, stream>>>(q_bf, k_bf, v_t, alibi, ctx_bf);

  // 5. output projection + bias + residual (fp32 out)
  gemm_nt_res<<<(SEQL / 128) * (HIDN / 128), 256, 0, stream>>>(
      ctx_bf, wd_bf, SEQL, HIDN, HIDN, bd, residual, out);
}